// Round 12
// baseline (367.715 us; speedup 1.0000x reference)
//
#include <hip/hip_runtime.h>

#define NITERS 50

typedef __attribute__((ext_vector_type(4))) float f32x4;
typedef __attribute__((ext_vector_type(8))) _Float16 f16x8;
typedef __attribute__((ext_vector_type(4))) _Float16 f16x4;

// ---- LDS: one 36864-byte arena (18432 shorts) ----
// setup (per pass, <=128 rows): sth[row][72] halves [0,9216), stl [9216,18432)
// steady state:
//   bT  f32 [8][204]          floats [0,1632)    (stores b * log2e)
//   sqp f32 [4][8]            floats [1640,1672)
//   eF  halves [28 grp][136]  halves [3400,7208)  N-packed [eh|el], +8 pad/grp
//   znF halves [8 grp][136]   halves [7208,8296)  N-packed [zh|zl]
//   SEP f32 [8][4]            floats [4160,4192)  Se row-partials
//   MX  f32 [4][8]            floats [4200,4232)  per-wave b-max per k
#define STL_OFF 9216
#define SQP_F 1640
#define EF_H 3400
#define ZN_H 7208
#define SEP_F 4160
#define MX_F 4200

#define L2E 1.44269504f

struct HL {
  _Float16 h, l;
};
__device__ __forceinline__ HL split2(float x) {
  HL r;
  r.h = (_Float16)x;
  r.l = (_Float16)(x - (float)r.h);
  return r;
}

// DPP lane-rotation within 16-lane rows (VALU, not LDS pipe).
template <int CTRL>
__device__ __forceinline__ float dppmv(float x) {
  return __int_as_float(__builtin_amdgcn_update_dpp(
      0, __float_as_int(x), CTRL, 0xF, 0xF, true));
}
__device__ __forceinline__ float swz16(float x) {  // xor 16 (LDS pipe)
  return __int_as_float(
      __builtin_amdgcn_ds_swizzle(__float_as_int(x), 0x401F));
}
__device__ __forceinline__ float wave_red_max(float x) {  // one-time init use
  x = fmaxf(x, dppmv<0x121>(x));
  x = fmaxf(x, dppmv<0x122>(x));
  x = fmaxf(x, dppmv<0x124>(x));
  x = fmaxf(x, dppmv<0x128>(x));
  x = fmaxf(x, swz16(x));
  x = fmaxf(x, __shfl_xor(x, 32, 64));
  return x;
}

__global__ __launch_bounds__(256, 3) void mie9(
    const float* __restrict__ gin, const float* __restrict__ gW,
    const float* __restrict__ gbias, const float* __restrict__ gb0,
    float* __restrict__ gout) {
  __shared__ short arena[18432];
  float* smF = (float*)arena;
  _Float16* smH = (_Float16*)arena;
  _Float16* sth = smH;
  _Float16* stl = smH + STL_OFF;

  const int b = blockIdx.x;
  const int tid = threadIdx.x;
  const int wv = tid >> 6;
  const int lane = tid & 63;
  const int col = lane & 15;
  const int oct = lane >> 4;
  const int kcol = col & 7;
  const int d0 = wv * 16;

  // ---- W fragments (hi/lo), bias ----
  f16x8 wh[2], wl[2];
#pragma unroll
  for (int c = 0; c < 2; ++c)
#pragma unroll
    for (int j = 0; j < 8; ++j) {
      HL t = split2(gW[(32 * c + oct * 8 + j) * 64 + d0 + col]);
      wh[c][j] = t.h;
      wl[c][j] = t.l;
    }
  float biasc = gbias[d0 + col];
  const float* ginb = gin + (size_t)b * 12800;

  f16x8 vBh[7], vBl[7];
  f16x8 vCh[4][2], vCl[4][2];

  // ---- v = in @ W + bias, staged in two s-passes ----
  auto compute_rows = [&](int mtA, int mtB, int rb) {
#pragma unroll 2
    for (int mt = mtA; mt < mtB; ++mt) {
      int sa = mt * 16 + col;
      f16x8 ah[2] = {{}, {}}, al[2] = {{}, {}};
      if (sa < 200) {
#pragma unroll
        for (int c = 0; c < 2; ++c) {
          const float* p = ginb + sa * 64 + 32 * c + oct * 8;
          float4 x0 = *(const float4*)p;
          float4 x1 = *(const float4*)(p + 4);
          HL t0 = split2(x0.x), t1 = split2(x0.y), t2 = split2(x0.z),
             t3 = split2(x0.w);
          HL t4 = split2(x1.x), t5 = split2(x1.y), t6 = split2(x1.z),
             t7 = split2(x1.w);
          ah[c][0] = t0.h; al[c][0] = t0.l;
          ah[c][1] = t1.h; al[c][1] = t1.l;
          ah[c][2] = t2.h; al[c][2] = t2.l;
          ah[c][3] = t3.h; al[c][3] = t3.l;
          ah[c][4] = t4.h; al[c][4] = t4.l;
          ah[c][5] = t5.h; al[c][5] = t5.l;
          ah[c][6] = t6.h; al[c][6] = t6.l;
          ah[c][7] = t7.h; al[c][7] = t7.l;
        }
      }
      f32x4 acc = {0.f, 0.f, 0.f, 0.f};
#pragma unroll
      for (int c = 0; c < 2; ++c) {
        acc = __builtin_amdgcn_mfma_f32_16x16x32_f16(ah[c], wh[c], acc, 0, 0, 0);
        acc = __builtin_amdgcn_mfma_f32_16x16x32_f16(ah[c], wl[c], acc, 0, 0, 0);
        acc = __builtin_amdgcn_mfma_f32_16x16x32_f16(al[c], wh[c], acc, 0, 0, 0);
      }
#pragma unroll
      for (int r = 0; r < 4; ++r) {
        int so = mt * 16 + oct * 4 + r;
        if (so < 200) {
          HL t = split2(acc[r] + biasc);
          sth[(so - rb) * 72 + d0 + col] = t.h;
          stl[(so - rb) * 72 + d0 + col] = t.l;
        }
      }
    }
  };

  // pass 1: rows 0..127 (mt 0..7)
  compute_rows(0, 8, 0);
  __syncthreads();
#pragma unroll
  for (int t = 0; t < 4; ++t) {
#pragma unroll
    for (int j = 0; j < 8; ++j) {
      int sR = 32 * t + oct * 8 + j;
      vBh[t][j] = sth[sR * 72 + d0 + col];
      vBl[t][j] = stl[sR * 72 + d0 + col];
    }
  }
#pragma unroll
  for (int u = 0; u < 2; ++u) {
    int sR = (wv + 4 * u) * 16 + col;  // <= 127
#pragma unroll
    for (int c = 0; c < 2; ++c) {
      vCh[u][c] = *(const f16x8*)&sth[sR * 72 + 32 * c + oct * 8];
      vCl[u][c] = *(const f16x8*)&stl[sR * 72 + 32 * c + oct * 8];
    }
  }
  __syncthreads();

  // pass 2: rows 128..199 (mt 8..12)
  compute_rows(8, 13, 128);
  __syncthreads();
#pragma unroll
  for (int t = 4; t < 7; ++t) {
    if (t < 6 || oct == 0) {
#pragma unroll
      for (int j = 0; j < 8; ++j) {
        int sR = 32 * t + oct * 8 + j - 128;
        vBh[t][j] = sth[sR * 72 + d0 + col];
        vBl[t][j] = stl[sR * 72 + d0 + col];
      }
    } else {
      vBh[t] = f16x8{};
      vBl[t] = f16x8{};
    }
  }
#pragma unroll
  for (int u = 2; u < 4; ++u) {
    int mt = wv + 4 * u;
    if (mt < 13) {
      int sR = mt * 16 + col;
      if (sR > 199) sR = 199;  // dup rows feed unstored D rows only
      sR -= 128;
#pragma unroll
      for (int c = 0; c < 2; ++c) {
        vCh[u][c] = *(const f16x8*)&sth[sR * 72 + 32 * c + oct * 8];
        vCl[u][c] = *(const f16x8*)&stl[sR * 72 + 32 * c + oct * 8];
      }
    } else {
#pragma unroll
      for (int c = 0; c < 2; ++c) {
        vCh[u][c] = f16x8{};
        vCl[u][c] = f16x8{};
      }
    }
  }
  __syncthreads();

  // ---- stage b_init * log2e -> bT[k][s] fp32 ----
  const float* gb = gb0 + (size_t)b * 1600;
  for (int idx = tid; idx < 1600; idx += 256)
    smF[(idx & 7) * 204 + (idx >> 3)] = gb[idx] * L2E;
  __syncthreads();

  // ---- one-time init of MX[wv][k] (max over s of b') ----
#pragma unroll
  for (int ki = 0; ki < 2; ++ki) {
    int kk = 2 * wv + ki;
    float4 bv;
    if (lane < 50)
      bv = *(const float4*)&smF[kk * 204 + 4 * lane];
    else
      bv = make_float4(-3e38f, -3e38f, -3e38f, -3e38f);
    float mx = wave_red_max(fmaxf(fmaxf(bv.x, bv.y), fmaxf(bv.z, bv.w)));
    if (lane == 0) {
      smF[MX_F + kk] = mx;
      smF[MX_F + 8 + kk] = mx;
      smF[MX_F + 16 + kk] = mx;
      smF[MX_F + 24 + kk] = mx;
    }
  }
  __syncthreads();

  // ---- per-iteration phase lambdas ----
  auto phaseA = [&]() {
#pragma unroll
    for (int ki = 0; ki < 2; ++ki) {
      int kk = 2 * wv + ki;
      float mx01 = fmaxf(smF[MX_F + kk], smF[MX_F + 8 + kk]);
      float mx23 = fmaxf(smF[MX_F + 16 + kk], smF[MX_F + 24 + kk]);
      float mxa = fmaxf(mx01, mx23) - 12.f;
      float4 bv;
      if (lane < 50)
        bv = *(const float4*)&smF[kk * 204 + 4 * lane];
      else
        bv = make_float4(-3e38f, -3e38f, -3e38f, -3e38f);
      float e0 = exp2f(bv.x - mxa);
      float e1 = exp2f(bv.y - mxa);
      float e2 = exp2f(bv.z - mxa);
      float e3 = exp2f(bv.w - mxa);
      HL s0 = split2(e0), s1 = split2(e1), s2 = split2(e2), s3 = split2(e3);
      f16x4 hv, lv;
      hv[0] = s0.h; lv[0] = s0.l;
      hv[1] = s1.h; lv[1] = s1.l;
      hv[2] = s2.h; lv[2] = s2.l;
      hv[3] = s3.h; lv[3] = s3.l;
      if (lane < 56) {  // lanes 50..55 store zeros -> tail rows stay zero
        int slot = (lane >> 1) * 136 + kk * 8 + (lane & 1) * 4;
        *(f16x4*)&smH[EF_H + slot] = hv;       // n = kk   (hi)
        *(f16x4*)&smH[EF_H + slot + 64] = lv;  // n = kk+8 (lo)
      }
      // Se row-partials: 4-dpp rotate-accumulate (all-VALU, low latency)
      float se = (e0 + e1) + (e2 + e3);
      se += dppmv<0x121>(se);
      se += dppmv<0x122>(se);
      se += dppmv<0x124>(se);
      se += dppmv<0x128>(se);  // every lane now holds its 16-row sum
      if ((lane & 15) == 0) smF[SEP_F + kk * 4 + oct] = se;
    }
  };

  auto phaseB = [&]() -> f32x4 {
    f32x4 z0 = {0.f, 0.f, 0.f, 0.f}, z1 = {0.f, 0.f, 0.f, 0.f};
#pragma unroll
    for (int t = 0; t < 7; ++t) {
      f16x8 ep = *(const f16x8*)&smH[EF_H + (t * 4 + oct) * 136 + col * 8];
      if (t & 1) {
        z1 = __builtin_amdgcn_mfma_f32_16x16x32_f16(vBh[t], ep, z1, 0, 0, 0);
        z1 = __builtin_amdgcn_mfma_f32_16x16x32_f16(vBl[t], ep, z1, 0, 0, 0);
      } else {
        z0 = __builtin_amdgcn_mfma_f32_16x16x32_f16(vBh[t], ep, z0, 0, 0, 0);
        z0 = __builtin_amdgcn_mfma_f32_16x16x32_f16(vBl[t], ep, z0, 0, 0, 0);
      }
    }
    f32x4 z = z0 + z1;
#pragma unroll
    for (int r = 0; r < 4; ++r) z[r] += dppmv<0x128>(z[r]);  // fold hi|lo
    float sq = z[0] * z[0] + z[1] * z[1] + z[2] * z[2] + z[3] * z[3];
    sq += swz16(sq);
    sq += __shfl_xor(sq, 32, 64);
    if (oct == 0 && col < 8) smF[SQP_F + wv * 8 + col] = sq;
    f16x4 st;
#pragma unroll
    for (int r = 0; r < 4; ++r) {
      float val = z[r] * (1.f / 4096.f);
      _Float16 h = (_Float16)val;
      st[r] = (col < 8) ? h : (_Float16)(val - (float)h);
    }
    int octf = (2 * wv + (oct >> 1)) & 3;
    int slot = ((wv >> 1) * 4 + octf) * 136 + col * 8 + (oct & 1) * 4;
    *(f16x4*)&smH[ZN_H + slot] = st;
    return z;
  };

  auto squash = [&]() -> float {
    float sqt = smF[SQP_F + kcol] + smF[SQP_F + 8 + kcol] +
                smF[SQP_F + 16 + kcol] + smF[SQP_F + 24 + kcol];
    float Se = (smF[SEP_F + kcol * 4 + 0] + smF[SEP_F + kcol * 4 + 1]) +
               (smF[SEP_F + kcol * 4 + 2] + smF[SEP_F + kcol * 4 + 3]);
    float rse = __builtin_amdgcn_rcpf(Se);
    float ns = sqt * 0.015625f * rse * rse;
    return ns * __builtin_amdgcn_rsqf(ns + 1e-9f) *
           __builtin_amdgcn_rcpf(1.f + ns) * rse;
  };

  // ================= routing iterations (49 update steps) =================
#pragma unroll 1
  for (int it = 0; it < NITERS - 1; ++it) {
    // preload this iter's bT operands for C (bT is stable until C writes it;
    // these float in flight across phases A and B)
    float4 bb0 = make_float4(0.f, 0.f, 0.f, 0.f), bb1 = bb0, bb2 = bb0;
    if (col < 8) {
      int sp = wv * 16 + 4 * oct;
      bb0 = *(const float4*)&smF[col * 204 + sp];
      bb1 = *(const float4*)&smF[col * 204 + sp + 64];
      bb2 = *(const float4*)&smF[col * 204 + sp + 128];
    }
    phaseA();
    __syncthreads();
    f32x4 z = phaseB();
    (void)z;
    __syncthreads();
    // issue zn fragment reads before the squash scalar chain
    f16x8 zf0 = *(const f16x8*)&smH[ZN_H + oct * 136 + col * 8];
    f16x8 zf1 = *(const f16x8*)&smH[ZN_H + (4 + oct) * 136 + col * 8];
    float cvC = squash() * (4096.f * L2E);  // b-state carries log2e
    float bmax = -3e38f;
    // ---- Phase C: bT[k][s] += cvC * (v . zn); track new b-max ----
#pragma unroll
    for (int u = 0; u < 3; ++u) {  // mt = wv, wv+4, wv+8 : always valid
      f32x4 a = {0.f, 0.f, 0.f, 0.f};
      a = __builtin_amdgcn_mfma_f32_16x16x32_f16(vCh[u][0], zf0, a, 0, 0, 0);
      a = __builtin_amdgcn_mfma_f32_16x16x32_f16(vCl[u][0], zf0, a, 0, 0, 0);
      a = __builtin_amdgcn_mfma_f32_16x16x32_f16(vCh[u][1], zf1, a, 0, 0, 0);
      a = __builtin_amdgcn_mfma_f32_16x16x32_f16(vCl[u][1], zf1, a, 0, 0, 0);
#pragma unroll
      for (int r = 0; r < 4; ++r) a[r] += dppmv<0x128>(a[r]);  // fold
      if (col < 8) {
        float4 bb = (u == 0) ? bb0 : (u == 1) ? bb1 : bb2;
        bb.x = fmaf(cvC, a[0], bb.x);
        bb.y = fmaf(cvC, a[1], bb.y);
        bb.z = fmaf(cvC, a[2], bb.z);
        bb.w = fmaf(cvC, a[3], bb.w);
        int sp = (wv + 4 * u) * 16 + 4 * oct;
        *(float4*)&smF[col * 204 + sp] = bb;
        bmax = fmaxf(bmax, fmaxf(fmaxf(bb.x, bb.y), fmaxf(bb.z, bb.w)));
      }
    }
    if (wv == 0) {  // u = 3: mt = 12, rows 192..199 only
      f32x4 a = {0.f, 0.f, 0.f, 0.f};
      a = __builtin_amdgcn_mfma_f32_16x16x32_f16(vCh[3][0], zf0, a, 0, 0, 0);
      a = __builtin_amdgcn_mfma_f32_16x16x32_f16(vCl[3][0], zf0, a, 0, 0, 0);
      a = __builtin_amdgcn_mfma_f32_16x16x32_f16(vCh[3][1], zf1, a, 0, 0, 0);
      a = __builtin_amdgcn_mfma_f32_16x16x32_f16(vCl[3][1], zf1, a, 0, 0, 0);
#pragma unroll
      for (int r = 0; r < 4; ++r) a[r] += dppmv<0x128>(a[r]);
      if (col < 8) {
        int sp = 192 + 4 * oct;
        if (sp < 200) {
          float* bp = &smF[col * 204 + sp];
          float4 bb = *(float4*)bp;
          bb.x = fmaf(cvC, a[0], bb.x);
          bb.y = fmaf(cvC, a[1], bb.y);
          bb.z = fmaf(cvC, a[2], bb.z);
          bb.w = fmaf(cvC, a[3], bb.w);
          *(float4*)bp = bb;
          bmax = fmaxf(bmax, fmaxf(fmaxf(bb.x, bb.y), fmaxf(bb.z, bb.w)));
        }
      }
    }
    // combine bmax across octs (col preserved by xor16/xor32), store MX
    bmax = fmaxf(bmax, swz16(bmax));
    bmax = fmaxf(bmax, __shfl_xor(bmax, 32, 64));
    if (lane < 8) smF[MX_F + wv * 8 + lane] = bmax;
    __syncthreads();
  }

  // ================= final pass: softmax + z + squash + readout ==========
  phaseA();
  __syncthreads();
  f32x4 z = phaseB();
  __syncthreads();
  float cv = squash();
  if (col < 8) {
    float4 u4;
    u4.x = cv * z[0];
    u4.y = cv * z[1];
    u4.z = cv * z[2];
    u4.w = cv * z[3];
    *(float4*)&gout[(size_t)b * 512 + col * 64 + 16 * wv + 4 * oct] = u4;
  }
}

extern "C" void kernel_launch(void* const* d_in, const int* in_sizes, int n_in,
                              void* d_out, int out_size, void* d_ws,
                              size_t ws_size, hipStream_t stream) {
  const float* gin = (const float*)d_in[0];
  const float* gW = (const float*)d_in[1];
  const float* gbias = (const float*)d_in[2];
  const float* gb0 = (const float*)d_in[3];
  float* gout = (float*)d_out;
  hipLaunchKernelGGL(mie9, dim3(2048), dim3(256), 0, stream, gin, gW, gbias,
                     gb0, gout);
}

// Round 13
// 351.885 us; speedup vs baseline: 1.0450x; 1.0450x over previous
//
#include <hip/hip_runtime.h>

#define NITERS 50

typedef __attribute__((ext_vector_type(4))) float f32x4;
typedef __attribute__((ext_vector_type(8))) _Float16 f16x8;
typedef __attribute__((ext_vector_type(4))) _Float16 f16x4;

// ---- LDS: one 36864-byte arena (18432 shorts) ----
// setup (per pass, <=128 rows): sth[row][72] halves [0,9216), stl [9216,18432)
// steady state:
//   bT  f32 [8][204]          floats [0,1632)    (stores b * log2e)
//   sqp f32 [4][8]            floats [1640,1672)
//   eF  halves [28 grp][136]  halves [3400,7208)  N-packed [eh|el], +8 pad/grp
//   znF halves [8 grp][136]   halves [7208,8296)  N-packed [zh|zl]
//   SEP f32 [8][4]            floats [4160,4192)  Se row-partials
//   MX  f32 [4][8]            floats [4200,4232)  per-wave b-max per k
#define STL_OFF 9216
#define SQP_F 1640
#define EF_H 3400
#define ZN_H 7208
#define SEP_F 4160
#define MX_F 4200

#define L2E 1.44269504f

struct HL {
  _Float16 h, l;
};
__device__ __forceinline__ HL split2(float x) {
  HL r;
  r.h = (_Float16)x;
  r.l = (_Float16)(x - (float)r.h);
  return r;
}

// DPP lane-rotation within 16-lane rows (VALU, not LDS pipe).
template <int CTRL>
__device__ __forceinline__ float dppmv(float x) {
  return __int_as_float(__builtin_amdgcn_update_dpp(
      0, __float_as_int(x), CTRL, 0xF, 0xF, true));
}
__device__ __forceinline__ float swz16(float x) {  // xor 16 (LDS pipe)
  return __int_as_float(
      __builtin_amdgcn_ds_swizzle(__float_as_int(x), 0x401F));
}
__device__ __forceinline__ float wave_red_max(float x) {  // one-time init use
  x = fmaxf(x, dppmv<0x121>(x));
  x = fmaxf(x, dppmv<0x122>(x));
  x = fmaxf(x, dppmv<0x124>(x));
  x = fmaxf(x, dppmv<0x128>(x));
  x = fmaxf(x, swz16(x));
  x = fmaxf(x, __shfl_xor(x, 32, 64));
  return x;
}

__global__ __launch_bounds__(256, 3) void mie10(
    const float* __restrict__ gin, const float* __restrict__ gW,
    const float* __restrict__ gbias, const float* __restrict__ gb0,
    float* __restrict__ gout) {
  __shared__ short arena[18432];
  float* smF = (float*)arena;
  _Float16* smH = (_Float16*)arena;
  _Float16* sth = smH;
  _Float16* stl = smH + STL_OFF;

  const int b = blockIdx.x;
  const int tid = threadIdx.x;
  const int wv = tid >> 6;
  const int lane = tid & 63;
  const int col = lane & 15;
  const int oct = lane >> 4;
  const int kcol = col & 7;
  const int d0 = wv * 16;

  // ---- W fragments (hi/lo), bias ----
  f16x8 wh[2], wl[2];
#pragma unroll
  for (int c = 0; c < 2; ++c)
#pragma unroll
    for (int j = 0; j < 8; ++j) {
      HL t = split2(gW[(32 * c + oct * 8 + j) * 64 + d0 + col]);
      wh[c][j] = t.h;
      wl[c][j] = t.l;
    }
  float biasc = gbias[d0 + col];
  const float* ginb = gin + (size_t)b * 12800;

  f16x8 vBh[7], vBl[7];
  f16x8 vCh[4][2], vCl[4][2];

  // ---- v = in @ W + bias, staged in two s-passes ----
  auto compute_rows = [&](int mtA, int mtB, int rb) {
#pragma unroll 2
    for (int mt = mtA; mt < mtB; ++mt) {
      int sa = mt * 16 + col;
      f16x8 ah[2] = {{}, {}}, al[2] = {{}, {}};
      if (sa < 200) {
#pragma unroll
        for (int c = 0; c < 2; ++c) {
          const float* p = ginb + sa * 64 + 32 * c + oct * 8;
          float4 x0 = *(const float4*)p;
          float4 x1 = *(const float4*)(p + 4);
          HL t0 = split2(x0.x), t1 = split2(x0.y), t2 = split2(x0.z),
             t3 = split2(x0.w);
          HL t4 = split2(x1.x), t5 = split2(x1.y), t6 = split2(x1.z),
             t7 = split2(x1.w);
          ah[c][0] = t0.h; al[c][0] = t0.l;
          ah[c][1] = t1.h; al[c][1] = t1.l;
          ah[c][2] = t2.h; al[c][2] = t2.l;
          ah[c][3] = t3.h; al[c][3] = t3.l;
          ah[c][4] = t4.h; al[c][4] = t4.l;
          ah[c][5] = t5.h; al[c][5] = t5.l;
          ah[c][6] = t6.h; al[c][6] = t6.l;
          ah[c][7] = t7.h; al[c][7] = t7.l;
        }
      }
      f32x4 acc = {0.f, 0.f, 0.f, 0.f};
#pragma unroll
      for (int c = 0; c < 2; ++c) {
        acc = __builtin_amdgcn_mfma_f32_16x16x32_f16(ah[c], wh[c], acc, 0, 0, 0);
        acc = __builtin_amdgcn_mfma_f32_16x16x32_f16(ah[c], wl[c], acc, 0, 0, 0);
        acc = __builtin_amdgcn_mfma_f32_16x16x32_f16(al[c], wh[c], acc, 0, 0, 0);
      }
#pragma unroll
      for (int r = 0; r < 4; ++r) {
        int so = mt * 16 + oct * 4 + r;
        if (so < 200) {
          HL t = split2(acc[r] + biasc);
          sth[(so - rb) * 72 + d0 + col] = t.h;
          stl[(so - rb) * 72 + d0 + col] = t.l;
        }
      }
    }
  };

  // pass 1: rows 0..127 (mt 0..7)
  compute_rows(0, 8, 0);
  __syncthreads();
#pragma unroll
  for (int t = 0; t < 4; ++t) {
#pragma unroll
    for (int j = 0; j < 8; ++j) {
      int sR = 32 * t + oct * 8 + j;
      vBh[t][j] = sth[sR * 72 + d0 + col];
      vBl[t][j] = stl[sR * 72 + d0 + col];
    }
  }
#pragma unroll
  for (int u = 0; u < 2; ++u) {
    int sR = (wv + 4 * u) * 16 + col;  // <= 127
#pragma unroll
    for (int c = 0; c < 2; ++c) {
      vCh[u][c] = *(const f16x8*)&sth[sR * 72 + 32 * c + oct * 8];
      vCl[u][c] = *(const f16x8*)&stl[sR * 72 + 32 * c + oct * 8];
    }
  }
  __syncthreads();

  // pass 2: rows 128..199 (mt 8..12)
  compute_rows(8, 13, 128);
  __syncthreads();
#pragma unroll
  for (int t = 4; t < 7; ++t) {
    if (t < 6 || oct == 0) {
#pragma unroll
      for (int j = 0; j < 8; ++j) {
        int sR = 32 * t + oct * 8 + j - 128;
        vBh[t][j] = sth[sR * 72 + d0 + col];
        vBl[t][j] = stl[sR * 72 + d0 + col];
      }
    } else {
      vBh[t] = f16x8{};
      vBl[t] = f16x8{};
    }
  }
#pragma unroll
  for (int u = 2; u < 4; ++u) {
    int mt = wv + 4 * u;
    if (mt < 13) {
      int sR = mt * 16 + col;
      if (sR > 199) sR = 199;  // dup rows feed unstored D rows only
      sR -= 128;
#pragma unroll
      for (int c = 0; c < 2; ++c) {
        vCh[u][c] = *(const f16x8*)&sth[sR * 72 + 32 * c + oct * 8];
        vCl[u][c] = *(const f16x8*)&stl[sR * 72 + 32 * c + oct * 8];
      }
    } else {
#pragma unroll
      for (int c = 0; c < 2; ++c) {
        vCh[u][c] = f16x8{};
        vCl[u][c] = f16x8{};
      }
    }
  }
  __syncthreads();

  // ---- stage b_init * log2e -> bT[k][s] fp32 ----
  const float* gb = gb0 + (size_t)b * 1600;
  for (int idx = tid; idx < 1600; idx += 256)
    smF[(idx & 7) * 204 + (idx >> 3)] = gb[idx] * L2E;
  __syncthreads();

  // ---- one-time init of MX[wv][k] (max over s of b') ----
#pragma unroll
  for (int ki = 0; ki < 2; ++ki) {
    int kk = 2 * wv + ki;
    float4 bv;
    if (lane < 50)
      bv = *(const float4*)&smF[kk * 204 + 4 * lane];
    else
      bv = make_float4(-3e38f, -3e38f, -3e38f, -3e38f);
    float mx = wave_red_max(fmaxf(fmaxf(bv.x, bv.y), fmaxf(bv.z, bv.w)));
    if (lane == 0) {
      smF[MX_F + kk] = mx;
      smF[MX_F + 8 + kk] = mx;
      smF[MX_F + 16 + kk] = mx;
      smF[MX_F + 24 + kk] = mx;
    }
  }
  __syncthreads();

  // ================= routing iterations =================
#pragma unroll 1
  for (int it = 0; it < NITERS; ++it) {
    // ---- Phase A: e' = 4096*2^(b'-max); max precomputed (lazy, phase C) ----
#pragma unroll
    for (int ki = 0; ki < 2; ++ki) {
      int kk = 2 * wv + ki;
      float mx01 = fmaxf(smF[MX_F + kk], smF[MX_F + 8 + kk]);
      float mx23 = fmaxf(smF[MX_F + 16 + kk], smF[MX_F + 24 + kk]);
      float mxa = fmaxf(mx01, mx23) - 12.f;
      float4 bv;
      if (lane < 50)
        bv = *(const float4*)&smF[kk * 204 + 4 * lane];
      else
        bv = make_float4(-3e38f, -3e38f, -3e38f, -3e38f);
      float e0 = exp2f(bv.x - mxa);
      float e1 = exp2f(bv.y - mxa);
      float e2 = exp2f(bv.z - mxa);
      float e3 = exp2f(bv.w - mxa);
      HL s0 = split2(e0), s1 = split2(e1), s2 = split2(e2), s3 = split2(e3);
      f16x4 hv, lv;
      hv[0] = s0.h; lv[0] = s0.l;
      hv[1] = s1.h; lv[1] = s1.l;
      hv[2] = s2.h; lv[2] = s2.l;
      hv[3] = s3.h; lv[3] = s3.l;
      if (lane < 56) {  // lanes 50..55 store zeros -> tail rows stay zero
        int slot = (lane >> 1) * 136 + kk * 8 + (lane & 1) * 4;
        *(f16x4*)&smH[EF_H + slot] = hv;       // n = kk   (hi)
        *(f16x4*)&smH[EF_H + slot + 64] = lv;  // n = kk+8 (lo)
      }
      // Se row-partials: 4-dpp rotate-accumulate (all-VALU, low latency)
      float se = (e0 + e1) + (e2 + e3);
      se += dppmv<0x121>(se);
      se += dppmv<0x122>(se);
      se += dppmv<0x124>(se);
      se += dppmv<0x128>(se);  // every lane now holds its 16-row sum
      if ((lane & 15) == 0) smF[SEP_F + kk * 4 + oct] = se;
    }
    __syncthreads();

    // ---- Phase B: z[d][k] = v . e, packed-N (2 MFMA chains, setprio) ----
    f32x4 zc0 = {0.f, 0.f, 0.f, 0.f}, zc1 = {0.f, 0.f, 0.f, 0.f};
    __builtin_amdgcn_s_setprio(1);
#pragma unroll
    for (int t = 0; t < 7; ++t) {
      f16x8 ep = *(const f16x8*)&smH[EF_H + (t * 4 + oct) * 136 + col * 8];
      if (t & 1) {
        zc1 = __builtin_amdgcn_mfma_f32_16x16x32_f16(vBh[t], ep, zc1, 0, 0, 0);
        zc1 = __builtin_amdgcn_mfma_f32_16x16x32_f16(vBl[t], ep, zc1, 0, 0, 0);
      } else {
        zc0 = __builtin_amdgcn_mfma_f32_16x16x32_f16(vBh[t], ep, zc0, 0, 0, 0);
        zc0 = __builtin_amdgcn_mfma_f32_16x16x32_f16(vBl[t], ep, zc0, 0, 0, 0);
      }
    }
    __builtin_amdgcn_s_setprio(0);
    f32x4 z = zc0 + zc1;
#pragma unroll
    for (int r = 0; r < 4; ++r) z[r] += dppmv<0x128>(z[r]);  // fold hi|lo
    // sum of squares (for squash), reduce across d-chunks (octs)
    float sq = z[0] * z[0] + z[1] * z[1] + z[2] * z[2] + z[3] * z[3];
    sq += swz16(sq);
    sq += __shfl_xor(sq, 32, 64);
    if (oct == 0 && col < 8) smF[SQP_F + wv * 8 + col] = sq;
    // store zn N-packed: col<8 lanes store hi-limb, col>=8 lanes lo-limb
    {
      f16x4 st;
#pragma unroll
      for (int r = 0; r < 4; ++r) {
        float val = z[r] * (1.f / 4096.f);
        _Float16 h = (_Float16)val;
        st[r] = (col < 8) ? h : (_Float16)(val - (float)h);
      }
      int octf = (2 * wv + (oct >> 1)) & 3;
      int slot = ((wv >> 1) * 4 + octf) * 136 + col * 8 + (oct & 1) * 4;
      *(f16x4*)&smH[ZN_H + slot] = st;
    }
    __syncthreads();

    // ---- squash scalars via native rcp/rsq (redundant per lane, k=kcol) ---
    float sqt = smF[SQP_F + kcol] + smF[SQP_F + 8 + kcol] +
                smF[SQP_F + 16 + kcol] + smF[SQP_F + 24 + kcol];
    float Se = (smF[SEP_F + kcol * 4 + 0] + smF[SEP_F + kcol * 4 + 1]) +
               (smF[SEP_F + kcol * 4 + 2] + smF[SEP_F + kcol * 4 + 3]);
    float rse = __builtin_amdgcn_rcpf(Se);
    float ns = sqt * 0.015625f * rse * rse;
    float cv = ns * __builtin_amdgcn_rsqf(ns + 1e-9f) *
               __builtin_amdgcn_rcpf(1.f + ns) * rse;

    if (it == NITERS - 1) {
      // final readout: u[k][d] = cv * z (z is 4096-scaled; cv absorbs it)
      if (col < 8) {
        float4 u4;
        u4.x = cv * z[0];
        u4.y = cv * z[1];
        u4.z = cv * z[2];
        u4.w = cv * z[3];
        *(float4*)&gout[(size_t)b * 512 + col * 64 + 16 * wv + 4 * oct] = u4;
      }
    } else {
      // ---- Phase C: bT[k][s] += cvC * (v . zn); also track new b-max ----
      float cvC = cv * (4096.f * L2E);  // b-state carries log2e
      f16x8 zf0 = *(const f16x8*)&smH[ZN_H + oct * 136 + col * 8];
      f16x8 zf1 = *(const f16x8*)&smH[ZN_H + (4 + oct) * 136 + col * 8];
      float bmax = -3e38f;
#pragma unroll
      for (int u = 0; u < 4; ++u) {
        int mt = wv + 4 * u;
        if (mt < 13) {
          f32x4 a = {0.f, 0.f, 0.f, 0.f};
          __builtin_amdgcn_s_setprio(1);
          a = __builtin_amdgcn_mfma_f32_16x16x32_f16(vCh[u][0], zf0, a, 0, 0, 0);
          a = __builtin_amdgcn_mfma_f32_16x16x32_f16(vCl[u][0], zf0, a, 0, 0, 0);
          a = __builtin_amdgcn_mfma_f32_16x16x32_f16(vCh[u][1], zf1, a, 0, 0, 0);
          a = __builtin_amdgcn_mfma_f32_16x16x32_f16(vCl[u][1], zf1, a, 0, 0, 0);
          __builtin_amdgcn_s_setprio(0);
#pragma unroll
          for (int r = 0; r < 4; ++r) a[r] += dppmv<0x128>(a[r]);  // fold
          if (col < 8) {
            int s0 = mt * 16 + 4 * oct;
            if (s0 < 200) {
              float* bp = &smF[col * 204 + s0];
              float4 bb = *(float4*)bp;
              bb.x = fmaf(cvC, a[0], bb.x);
              bb.y = fmaf(cvC, a[1], bb.y);
              bb.z = fmaf(cvC, a[2], bb.z);
              bb.w = fmaf(cvC, a[3], bb.w);
              *(float4*)bp = bb;
              bmax = fmaxf(
                  bmax, fmaxf(fmaxf(bb.x, bb.y), fmaxf(bb.z, bb.w)));
            }
          }
        }
      }
      // combine bmax across octs (col preserved by xor16/xor32), store MX
      bmax = fmaxf(bmax, swz16(bmax));
      bmax = fmaxf(bmax, __shfl_xor(bmax, 32, 64));
      if (lane < 8) smF[MX_F + wv * 8 + lane] = bmax;
    }
    __syncthreads();
  }
}

extern "C" void kernel_launch(void* const* d_in, const int* in_sizes, int n_in,
                              void* d_out, int out_size, void* d_ws,
                              size_t ws_size, hipStream_t stream) {
  const float* gin = (const float*)d_in[0];
  const float* gW = (const float*)d_in[1];
  const float* gbias = (const float*)d_in[2];
  const float* gb0 = (const float*)d_in[3];
  float* gout = (float*)d_out;
  hipLaunchKernelGGL(mie10, dim3(2048), dim3(256), 0, stream, gin, gW, gbias,
                     gb0, gout);
}